// Round 2
// baseline (4528.867 us; speedup 1.0000x reference)
//
#include <hip/hip_runtime.h>
#include <math.h>

#define NN 16384
#define FF 128
#define NRB 32
#define EE 262144
#define TE 32

__device__ __forceinline__ float silu_f(float x) { return x / (1.0f + expf(-x)); }
__device__ __forceinline__ int degmap(int j) { return (j == 0) ? 0 : (j < 4) ? 1 : (j < 9) ? 2 : 3; }

// ---------------------------------------------------------------------------
// Kernel 1: per-node projections q/k/v_inv (8 heads of 16x16), q/k_ev (4 of 32x32)
// ---------------------------------------------------------------------------
__global__ __launch_bounds__(128) void node_proj(
    const float* __restrict__ inv,
    const float* __restrict__ Wq_inv, const float* __restrict__ Wk_inv,
    const float* __restrict__ Wv_inv,
    const float* __restrict__ Wq_ev, const float* __restrict__ Wk_ev,
    float* __restrict__ q_inv, float* __restrict__ k_inv, float* __restrict__ v_inv,
    float* __restrict__ q_ev, float* __restrict__ k_ev)
{
    const int n = blockIdx.x;
    const int t = threadIdx.x;
    __shared__ float x[128];
    x[t] = inv[n * 128 + t];
    __syncthreads();

    {
        const int h = t >> 4, e = t & 15;
        const float* wq = Wq_inv + h * 256;
        const float* wk = Wk_inv + h * 256;
        const float* wv = Wv_inv + h * 256;
        float aq = 0.f, ak = 0.f, av = 0.f;
        #pragma unroll
        for (int d = 0; d < 16; ++d) {
            const float xv = x[h * 16 + d];
            aq += xv * wq[d * 16 + e];
            ak += xv * wk[d * 16 + e];
            av += xv * wv[d * 16 + e];
        }
        q_inv[n * 128 + t] = aq;
        k_inv[n * 128 + t] = ak;
        v_inv[n * 128 + t] = av;
    }
    {
        const int l = t >> 5, e = t & 31;
        const float* wq = Wq_ev + l * 1024;
        const float* wk = Wk_ev + l * 1024;
        float aq = 0.f, ak = 0.f;
        #pragma unroll
        for (int d = 0; d < 32; ++d) {
            const float xv = x[l * 32 + d];
            aq += xv * wq[d * 32 + e];
            ak += xv * wk[d * 32 + e];
        }
        q_ev[n * 128 + t] = aq;
        k_ev[n * 128 + t] = ak;
    }
}

// ---------------------------------------------------------------------------
// CSR build kernels
// ---------------------------------------------------------------------------
__global__ __launch_bounds__(256) void csr_count(const int* __restrict__ recv,
                                                 int* __restrict__ cnt) {
    const int e = blockIdx.x * 256 + threadIdx.x;
    if (e < EE) atomicAdd(&cnt[recv[e]], 1);
}

__global__ __launch_bounds__(256) void csr_scan(const int* __restrict__ cnt,
                                                int* __restrict__ off) {
    __shared__ int ps[256];
    const int t = threadIdx.x;
    const int base = t * 64;
    int s = 0;
    for (int i = 0; i < 64; ++i) s += cnt[base + i];
    ps[t] = s;
    __syncthreads();
    for (int dd = 1; dd < 256; dd <<= 1) {
        int v = 0;
        if (t >= dd) v = ps[t - dd];
        __syncthreads();
        ps[t] += v;
        __syncthreads();
    }
    int run = ps[t] - s;  // exclusive prefix
    for (int i = 0; i < 64; ++i) {
        off[base + i] = run;
        run += cnt[base + i];
    }
}

__global__ __launch_bounds__(256) void csr_fill(const int* __restrict__ recv,
                                                const int* __restrict__ send,
                                                const int* __restrict__ off,
                                                int* __restrict__ cursor,
                                                int* __restrict__ s_eid,
                                                int* __restrict__ s_sid) {
    const int e = blockIdx.x * 256 + threadIdx.x;
    if (e < EE) {
        const int r = recv[e];
        const int p = off[r] + atomicAdd(&cursor[r], 1);
        s_eid[p] = e;
        s_sid[p] = send[e];
    }
}

// ---------------------------------------------------------------------------
// Kernel 2: fused per-edge filter nets + attention alphas (NO scatter)
//   256 threads, TE=32 edges/block. Each thread owns a 4-edge x 4-col tile.
//   Output: alpha_g[e][16] = {8x cut*alpha_inv/sqrt16, 4x cut*alpha_ev/sqrt32, 0,0,0,0}
// ---------------------------------------------------------------------------
__global__ __launch_bounds__(256) void edge_kernel(
    const float* __restrict__ ev_feat,
    const float* __restrict__ rbf,
    const float* __restrict__ cutoffs,
    const int* __restrict__ senders,
    const int* __restrict__ receivers,
    const float* __restrict__ fi_w1r, const float* __restrict__ fi_b1r,
    const float* __restrict__ fi_w2r, const float* __restrict__ fi_b2r,
    const float* __restrict__ fi_w1e, const float* __restrict__ fi_b1e,
    const float* __restrict__ fi_w2e, const float* __restrict__ fi_b2e,
    const float* __restrict__ fe_w1r, const float* __restrict__ fe_b1r,
    const float* __restrict__ fe_w2r, const float* __restrict__ fe_b2r,
    const float* __restrict__ fe_w1e, const float* __restrict__ fe_b1e,
    const float* __restrict__ fe_w2e, const float* __restrict__ fe_b2e,
    const float* __restrict__ q_inv, const float* __restrict__ k_inv,
    const float* __restrict__ q_ev, const float* __restrict__ k_ev,
    float* __restrict__ alpha_g)
{
    __shared__ float h1[TE][128];
    __shared__ float wbuf[32][128];
    __shared__ float rbf_t[TE][NRB];
    __shared__ float he1[TE][32];
    __shared__ float evinv_t[TE][4];
    __shared__ float w1e_s[128];
    __shared__ float alpha_s[TE][16];
    __shared__ int sidx[TE];
    __shared__ int ridx[TE];
    __shared__ float cut[TE];

    const int tid = threadIdx.x;
    const int e0 = blockIdx.x * TE;

    if (tid < TE) {
        sidx[tid] = senders[e0 + tid];
        ridx[tid] = receivers[e0 + tid];
        cut[tid] = cutoffs[e0 + tid];
    }
    for (int i = tid; i < TE * NRB; i += 256)
        rbf_t[i >> 5][i & 31] = rbf[e0 * NRB + i];
    __syncthreads();

    if (tid < TE) {
        const float* es = ev_feat + sidx[tid] * 16;
        const float* er = ev_feat + ridx[tid] * 16;
        float d = es[0] - er[0];
        evinv_t[tid][0] = d * d;
        float a = 0.f;
        for (int j = 1; j < 4; ++j) { d = es[j] - er[j]; a += d * d; }
        evinv_t[tid][1] = a;
        a = 0.f;
        for (int j = 4; j < 9; ++j) { d = es[j] - er[j]; a += d * d; }
        evinv_t[tid][2] = a;
        a = 0.f;
        for (int j = 9; j < 16; ++j) { d = es[j] - er[j]; a += d * d; }
        evinv_t[tid][3] = a;
    }

    const int eg = tid >> 5;   // 0..7 : edge group (4 edges each)
    const int cg = tid & 31;   // 0..31: col group (4 cols each)
    const int cb = cg * 4;

    for (int p = 0; p < 2; ++p) {
        const float* w1r = p ? fe_w1r : fi_w1r;
        const float* b1r = p ? fe_b1r : fi_b1r;
        const float* w2r = p ? fe_w2r : fi_w2r;
        const float* b2r = p ? fe_b2r : fi_b2r;
        const float* w1e = p ? fe_w1e : fi_w1e;
        const float* b1e = p ? fe_b1e : fi_b1e;
        const float* w2e = p ? fe_w2e : fi_w2e;
        const float* b2e = p ? fe_b2e : fi_b2e;

        for (int i = tid; i < 32 * 128; i += 256) wbuf[i >> 7][i & 127] = w1r[i];
        if (tid < 128) w1e_s[tid] = w1e[tid];
        __syncthreads();

        // stage 1: h1 = silu(rbf @ w1r + b1r)
        {
            float hacc[4][4];
            float bj0 = b1r[cb], bj1 = b1r[cb + 1], bj2 = b1r[cb + 2], bj3 = b1r[cb + 3];
            #pragma unroll
            for (int i = 0; i < 4; ++i) {
                hacc[i][0] = bj0; hacc[i][1] = bj1; hacc[i][2] = bj2; hacc[i][3] = bj3;
            }
            for (int k = 0; k < 32; ++k) {
                const float4 w4 = *reinterpret_cast<const float4*>(&wbuf[k][cb]);
                #pragma unroll
                for (int i = 0; i < 4; ++i) {
                    const float xv = rbf_t[eg * 4 + i][k];
                    hacc[i][0] += xv * w4.x; hacc[i][1] += xv * w4.y;
                    hacc[i][2] += xv * w4.z; hacc[i][3] += xv * w4.w;
                }
            }
            #pragma unroll
            for (int i = 0; i < 4; ++i) {
                float4 hv;
                hv.x = silu_f(hacc[i][0]); hv.y = silu_f(hacc[i][1]);
                hv.z = silu_f(hacc[i][2]); hv.w = silu_f(hacc[i][3]);
                *reinterpret_cast<float4*>(&h1[eg * 4 + i][cb]) = hv;
            }
        }
        for (int i = tid; i < TE * 32; i += 256) {
            const int e = i >> 5, j2 = i & 31;
            float a = b1e[j2];
            #pragma unroll
            for (int k = 0; k < 4; ++k) a += evinv_t[e][k] * w1e_s[k * 32 + j2];
            he1[e][j2] = silu_f(a);
        }
        __syncthreads();

        // stage 2: fw = h1 @ w2r + he1 @ w2e + b2r + b2e (kept in registers)
        float acc[4][4];
        {
            const float b0 = b2r[cb] + b2e[cb];
            const float b1 = b2r[cb + 1] + b2e[cb + 1];
            const float b2 = b2r[cb + 2] + b2e[cb + 2];
            const float b3 = b2r[cb + 3] + b2e[cb + 3];
            #pragma unroll
            for (int i = 0; i < 4; ++i) {
                acc[i][0] = b0; acc[i][1] = b1; acc[i][2] = b2; acc[i][3] = b3;
            }
        }
        for (int cc = 0; cc < 4; ++cc) {
            for (int i = tid; i < 32 * 128; i += 256) wbuf[i >> 7][i & 127] = w2r[cc * 4096 + i];
            __syncthreads();
            for (int kk = 0; kk < 32; ++kk) {
                const float4 w4 = *reinterpret_cast<const float4*>(&wbuf[kk][cb]);
                #pragma unroll
                for (int i = 0; i < 4; ++i) {
                    const float xv = h1[eg * 4 + i][cc * 32 + kk];
                    acc[i][0] += xv * w4.x; acc[i][1] += xv * w4.y;
                    acc[i][2] += xv * w4.z; acc[i][3] += xv * w4.w;
                }
            }
            __syncthreads();
        }
        for (int i = tid; i < 32 * 128; i += 256) wbuf[i >> 7][i & 127] = w2e[i];
        __syncthreads();
        for (int kk = 0; kk < 32; ++kk) {
            const float4 w4 = *reinterpret_cast<const float4*>(&wbuf[kk][cb]);
            #pragma unroll
            for (int i = 0; i < 4; ++i) {
                const float xv = he1[eg * 4 + i][kk];
                acc[i][0] += xv * w4.x; acc[i][1] += xv * w4.y;
                acc[i][2] += xv * w4.z; acc[i][3] += xv * w4.w;
            }
        }
        __syncthreads();

        // attention alphas (no value scatter)
        if (p == 0) {
            // inv: head h = cg>>2 (cols 4cg..4cg+3, head = col/16)
            #pragma unroll
            for (int i = 0; i < 4; ++i) {
                const int e = eg * 4 + i;
                const int s = sidx[e], r = ridx[e];
                const float4 q4 = *reinterpret_cast<const float4*>(q_inv + r * 128 + cb);
                const float4 k4 = *reinterpret_cast<const float4*>(k_inv + s * 128 + cb);
                float part = q4.x * k4.x * acc[i][0] + q4.y * k4.y * acc[i][1]
                           + q4.z * k4.z * acc[i][2] + q4.w * k4.w * acc[i][3];
                part += __shfl_xor(part, 1);
                part += __shfl_xor(part, 2);
                if ((cg & 3) == 0)
                    alpha_s[e][cg >> 2] = part * 0.25f * cut[e];   // /sqrt(16)*cutoff
            }
        } else {
            // ev: degree l = cg>>3 (cols 4cg..4cg+3, degree = col/32)
            #pragma unroll
            for (int i = 0; i < 4; ++i) {
                const int e = eg * 4 + i;
                const int s = sidx[e], r = ridx[e];
                const float4 q4 = *reinterpret_cast<const float4*>(q_ev + r * 128 + cb);
                const float4 k4 = *reinterpret_cast<const float4*>(k_ev + s * 128 + cb);
                float part = q4.x * k4.x * acc[i][0] + q4.y * k4.y * acc[i][1]
                           + q4.z * k4.z * acc[i][2] + q4.w * k4.w * acc[i][3];
                part += __shfl_xor(part, 1);
                part += __shfl_xor(part, 2);
                part += __shfl_xor(part, 4);
                if ((cg & 7) == 0)
                    alpha_s[e][8 + (cg >> 3)] = part * 0.17677669529663687f * cut[e];
            }
        }
        __syncthreads();
    }

    // coalesced write of per-edge alpha records (64B each)
    for (int i = tid; i < TE * 16; i += 256) {
        const int j = i & 15;
        alpha_g[e0 * 16 + i] = (j < 12) ? alpha_s[i >> 4][j] : 0.f;
    }
}

// ---------------------------------------------------------------------------
// Kernel 3: per-node gather (CSR) + final 132x132 MLP, fused
// ---------------------------------------------------------------------------
__global__ __launch_bounds__(128) void node_update(
    const float* __restrict__ inv, const float* __restrict__ ev,
    const float* __restrict__ v_inv, const float* __restrict__ sh,
    const float* __restrict__ alpha_g,
    const int* __restrict__ cnt, const int* __restrict__ off,
    const int* __restrict__ s_eid, const int* __restrict__ s_sid,
    const float* __restrict__ int_w, const float* __restrict__ int_b,
    float* __restrict__ out0, float* __restrict__ out1)
{
    const int n = blockIdx.x;
    const int t = threadIdx.x;
    const int d = cnt[n];
    const int o = off[n];

    float acc_inv = 0.f;
    float acc_ev = 0.f;
    const int hsel = t >> 4;                 // which alpha word (0..7)
    const int esel = (t < 16) ? (8 + degmap(t)) : 0;

    for (int i = 0; i < d; ++i) {
        const int p = o + i;
        const int eid = s_eid[p];
        const int sid = s_sid[p];
        const float al = alpha_g[eid * 16 + hsel];
        acc_inv += al * v_inv[sid * 128 + t];
        if (t < 16) {
            const float ae = alpha_g[eid * 16 + esel];
            acc_ev += ae * sh[eid * 16 + t];
        }
    }

    __shared__ float xin[132];
    __shared__ float ev1s[16];
    __shared__ float tcol[4];

    const float iv = inv[n * 128 + t] + acc_inv;
    xin[t] = iv;
    if (t < 16) ev1s[t] = ev[n * 16 + t] + acc_ev;
    __syncthreads();
    if (t < 4) {
        const int st = (t == 0) ? 0 : (t == 1) ? 1 : (t == 2) ? 4 : 9;
        const int en = (t == 0) ? 1 : (t == 1) ? 4 : (t == 2) ? 9 : 16;
        float a = 0.f;
        for (int j = st; j < en; ++j) a += ev1s[j] * ev1s[j];
        xin[128 + t] = a;
    }
    __syncthreads();

    float acc = int_b[t];
    for (int k = 0; k < 132; ++k) acc += xin[k] * int_w[k * 132 + t];
    out0[n * 128 + t] = iv + acc;

    if (t < 4) {
        float a2 = int_b[128 + t];
        for (int k = 0; k < 132; ++k) a2 += xin[k] * int_w[k * 132 + 128 + t];
        tcol[t] = a2;
    }
    __syncthreads();
    if (t < 16) out1[n * 16 + t] = ev1s[t] * (1.0f + tcol[degmap(t)]);
}

// ---------------------------------------------------------------------------
extern "C" void kernel_launch(void* const* d_in, const int* in_sizes, int n_in,
                              void* d_out, int out_size, void* d_ws, size_t ws_size,
                              hipStream_t stream) {
    const float* inv_features = (const float*)d_in[0];
    const float* ev_features  = (const float*)d_in[1];
    const float* rbf          = (const float*)d_in[2];
    const float* sh_vectors   = (const float*)d_in[3];
    const float* cutoffs      = (const float*)d_in[4];
    const int*   senders      = (const int*)d_in[5];
    const int*   receivers    = (const int*)d_in[6];
    const float* fi_rbf_w1 = (const float*)d_in[7];
    const float* fi_rbf_b1 = (const float*)d_in[8];
    const float* fi_rbf_w2 = (const float*)d_in[9];
    const float* fi_rbf_b2 = (const float*)d_in[10];
    const float* fi_ev_w1  = (const float*)d_in[11];
    const float* fi_ev_b1  = (const float*)d_in[12];
    const float* fi_ev_w2  = (const float*)d_in[13];
    const float* fi_ev_b2  = (const float*)d_in[14];
    const float* fe_rbf_w1 = (const float*)d_in[15];
    const float* fe_rbf_b1 = (const float*)d_in[16];
    const float* fe_rbf_w2 = (const float*)d_in[17];
    const float* fe_rbf_b2 = (const float*)d_in[18];
    const float* fe_ev_w1  = (const float*)d_in[19];
    const float* fe_ev_b1  = (const float*)d_in[20];
    const float* fe_ev_w2  = (const float*)d_in[21];
    const float* fe_ev_b2  = (const float*)d_in[22];
    const float* Wq_inv = (const float*)d_in[23];
    const float* Wk_inv = (const float*)d_in[24];
    const float* Wv_inv = (const float*)d_in[25];
    const float* Wq_ev  = (const float*)d_in[26];
    const float* Wk_ev  = (const float*)d_in[27];
    const float* int_w  = (const float*)d_in[28];
    const float* int_b  = (const float*)d_in[29];

    float* ws = (float*)d_ws;
    float* q_inv   = ws;
    float* k_inv   = ws + (size_t)NN * 128;
    float* v_inv   = ws + (size_t)NN * 256;
    float* q_ev    = ws + (size_t)NN * 384;
    float* k_ev    = ws + (size_t)NN * 512;
    float* alpha_g = ws + (size_t)NN * 640;              // E*16 = NN*256 floats
    int*   cnt     = (int*)(ws + (size_t)NN * 896);      // NN
    int*   off     = cnt + NN;                            // NN
    int*   cursor  = cnt + 2 * NN;                        // NN
    int*   s_eid   = cnt + 3 * NN;                        // EE
    int*   s_sid   = s_eid + EE;                          // EE

    // zero histogram counters + cursors (contiguous: cnt, off, cursor)
    hipMemsetAsync(cnt, 0, (size_t)3 * NN * sizeof(int), stream);

    node_proj<<<NN, 128, 0, stream>>>(inv_features, Wq_inv, Wk_inv, Wv_inv,
                                      Wq_ev, Wk_ev, q_inv, k_inv, v_inv, q_ev, k_ev);

    csr_count<<<EE / 256, 256, 0, stream>>>(receivers, cnt);
    csr_scan<<<1, 256, 0, stream>>>(cnt, off);
    csr_fill<<<EE / 256, 256, 0, stream>>>(receivers, senders, off, cursor, s_eid, s_sid);

    edge_kernel<<<EE / TE, 256, 0, stream>>>(
        ev_features, rbf, cutoffs, senders, receivers,
        fi_rbf_w1, fi_rbf_b1, fi_rbf_w2, fi_rbf_b2,
        fi_ev_w1, fi_ev_b1, fi_ev_w2, fi_ev_b2,
        fe_rbf_w1, fe_rbf_b1, fe_rbf_w2, fe_rbf_b2,
        fe_ev_w1, fe_ev_b1, fe_ev_w2, fe_ev_b2,
        q_inv, k_inv, q_ev, k_ev, alpha_g);

    node_update<<<NN, 128, 0, stream>>>(inv_features, ev_features, v_inv, sh_vectors,
                                        alpha_g, cnt, off, s_eid, s_sid,
                                        int_w, int_b,
                                        (float*)d_out, (float*)d_out + (size_t)NN * 128);
}

// Round 3
// 710.302 us; speedup vs baseline: 6.3760x; 6.3760x over previous
//
#include <hip/hip_runtime.h>
#include <math.h>

#define NN 16384
#define FF 128
#define NRB 32
#define EE 262144
#define TE 32

__device__ __forceinline__ float silu_f(float x) { return x / (1.0f + expf(-x)); }
__device__ __forceinline__ int degmap(int j) { return (j == 0) ? 0 : (j < 4) ? 1 : (j < 9) ? 2 : 3; }

#define FMA_ROW(ACC, XS, W) { ACC[0] += (XS)*(W).x; ACC[1] += (XS)*(W).y; ACC[2] += (XS)*(W).z; ACC[3] += (XS)*(W).w; }

// ---------------------------------------------------------------------------
// Kernel 1: per-node projections q/k/v_inv (8 heads of 16x16), q/k_ev (4 of 32x32)
// ---------------------------------------------------------------------------
__global__ __launch_bounds__(128) void node_proj(
    const float* __restrict__ inv,
    const float* __restrict__ Wq_inv, const float* __restrict__ Wk_inv,
    const float* __restrict__ Wv_inv,
    const float* __restrict__ Wq_ev, const float* __restrict__ Wk_ev,
    float* __restrict__ q_inv, float* __restrict__ k_inv, float* __restrict__ v_inv,
    float* __restrict__ q_ev, float* __restrict__ k_ev)
{
    const int n = blockIdx.x;
    const int t = threadIdx.x;
    __shared__ float x[128];
    x[t] = inv[n * 128 + t];
    __syncthreads();

    {
        const int h = t >> 4, e = t & 15;
        const float* wq = Wq_inv + h * 256;
        const float* wk = Wk_inv + h * 256;
        const float* wv = Wv_inv + h * 256;
        float aq = 0.f, ak = 0.f, av = 0.f;
        #pragma unroll
        for (int d = 0; d < 16; ++d) {
            const float xv = x[h * 16 + d];
            aq += xv * wq[d * 16 + e];
            ak += xv * wk[d * 16 + e];
            av += xv * wv[d * 16 + e];
        }
        q_inv[n * 128 + t] = aq;
        k_inv[n * 128 + t] = ak;
        v_inv[n * 128 + t] = av;
    }
    {
        const int l = t >> 5, e = t & 31;
        const float* wq = Wq_ev + l * 1024;
        const float* wk = Wk_ev + l * 1024;
        float aq = 0.f, ak = 0.f;
        #pragma unroll
        for (int d = 0; d < 32; ++d) {
            const float xv = x[l * 32 + d];
            aq += xv * wq[d * 32 + e];
            ak += xv * wk[d * 32 + e];
        }
        q_ev[n * 128 + t] = aq;
        k_ev[n * 128 + t] = ak;
    }
}

// ---------------------------------------------------------------------------
// CSR build kernels
// ---------------------------------------------------------------------------
__global__ __launch_bounds__(256) void csr_count(const int* __restrict__ recv,
                                                 int* __restrict__ cnt) {
    const int e = blockIdx.x * 256 + threadIdx.x;
    if (e < EE) atomicAdd(&cnt[recv[e]], 1);
}

__global__ __launch_bounds__(256) void csr_scan(const int* __restrict__ cnt,
                                                int* __restrict__ off) {
    __shared__ int ps[256];
    const int t = threadIdx.x;
    const int base = t * 64;
    int s = 0;
    for (int i = 0; i < 64; ++i) s += cnt[base + i];
    ps[t] = s;
    __syncthreads();
    for (int dd = 1; dd < 256; dd <<= 1) {
        int v = 0;
        if (t >= dd) v = ps[t - dd];
        __syncthreads();
        ps[t] += v;
        __syncthreads();
    }
    int run = ps[t] - s;  // exclusive prefix
    for (int i = 0; i < 64; ++i) {
        off[base + i] = run;
        run += cnt[base + i];
    }
}

__global__ __launch_bounds__(256) void csr_fill(const int* __restrict__ recv,
                                                const int* __restrict__ send,
                                                const int* __restrict__ off,
                                                int* __restrict__ cursor,
                                                int* __restrict__ s_eid,
                                                int* __restrict__ s_sid) {
    const int e = blockIdx.x * 256 + threadIdx.x;
    if (e < EE) {
        const int r = recv[e];
        const int p = off[r] + atomicAdd(&cursor[r], 1);
        s_eid[p] = e;
        s_sid[p] = send[e];
    }
}

// ---------------------------------------------------------------------------
// Kernel 2: fused per-edge filter nets + attention alphas
//   256 threads, TE=32 edges/block, thread = 4 edges x 4 cols.
//   Inner loops: explicit k-step-4 float4 chunks, capped unroll (anti-spill).
// ---------------------------------------------------------------------------
__global__ __launch_bounds__(256) void edge_kernel(
    const float* __restrict__ ev_feat,
    const float* __restrict__ rbf,
    const float* __restrict__ cutoffs,
    const int* __restrict__ senders,
    const int* __restrict__ receivers,
    const float* __restrict__ fi_w1r, const float* __restrict__ fi_b1r,
    const float* __restrict__ fi_w2r, const float* __restrict__ fi_b2r,
    const float* __restrict__ fi_w1e, const float* __restrict__ fi_b1e,
    const float* __restrict__ fi_w2e, const float* __restrict__ fi_b2e,
    const float* __restrict__ fe_w1r, const float* __restrict__ fe_b1r,
    const float* __restrict__ fe_w2r, const float* __restrict__ fe_b2r,
    const float* __restrict__ fe_w1e, const float* __restrict__ fe_b1e,
    const float* __restrict__ fe_w2e, const float* __restrict__ fe_b2e,
    const float* __restrict__ q_inv, const float* __restrict__ k_inv,
    const float* __restrict__ q_ev, const float* __restrict__ k_ev,
    float* __restrict__ alpha_g)
{
    __shared__ float h1[TE][128];
    __shared__ float wbuf[32][128];
    __shared__ float rbf_t[TE][NRB];
    __shared__ float he1[TE][32];
    __shared__ float evinv_t[TE][4];
    __shared__ float w1e_s[128];
    __shared__ float alpha_s[TE][16];
    __shared__ int sidx[TE];
    __shared__ int ridx[TE];
    __shared__ float cut[TE];

    const int tid = threadIdx.x;
    const int e0 = blockIdx.x * TE;

    if (tid < TE) {
        sidx[tid] = senders[e0 + tid];
        ridx[tid] = receivers[e0 + tid];
        cut[tid] = cutoffs[e0 + tid];
    }
    // rbf tile: 32 edges x 32 = 256 float4
    {
        const float4* src = reinterpret_cast<const float4*>(rbf + (size_t)e0 * NRB);
        float4* dst = reinterpret_cast<float4*>(&rbf_t[0][0]);
        if (tid < 256) dst[tid] = src[tid];
    }
    __syncthreads();

    if (tid < TE) {
        const float* es = ev_feat + sidx[tid] * 16;
        const float* er = ev_feat + ridx[tid] * 16;
        float d = es[0] - er[0];
        evinv_t[tid][0] = d * d;
        float a = 0.f;
        for (int j = 1; j < 4; ++j) { d = es[j] - er[j]; a += d * d; }
        evinv_t[tid][1] = a;
        a = 0.f;
        for (int j = 4; j < 9; ++j) { d = es[j] - er[j]; a += d * d; }
        evinv_t[tid][2] = a;
        a = 0.f;
        for (int j = 9; j < 16; ++j) { d = es[j] - er[j]; a += d * d; }
        evinv_t[tid][3] = a;
    }

    const int eg = tid >> 5;   // 0..7 : edge group (4 edges each)
    const int cg = tid & 31;   // 0..31: col group (4 cols each)
    const int cb = cg * 4;
    const int e4 = eg * 4;

    for (int p = 0; p < 2; ++p) {
        const float* w1r = p ? fe_w1r : fi_w1r;
        const float* b1r = p ? fe_b1r : fi_b1r;
        const float* w2r = p ? fe_w2r : fi_w2r;
        const float* b2r = p ? fe_b2r : fi_b2r;
        const float* w1e = p ? fe_w1e : fi_w1e;
        const float* b1e = p ? fe_b1e : fi_b1e;
        const float* w2e = p ? fe_w2e : fi_w2e;
        const float* b2e = p ? fe_b2e : fi_b2e;

        // stage w1r (32x128) as float4
        {
            const float4* src = reinterpret_cast<const float4*>(w1r);
            float4* dst = reinterpret_cast<float4*>(&wbuf[0][0]);
            #pragma unroll
            for (int i = 0; i < 4; ++i) dst[tid + 256 * i] = src[tid + 256 * i];
        }
        if (tid < 128) w1e_s[tid] = w1e[tid];
        __syncthreads();

        // ---- stage 1: h1 = silu(rbf @ w1r + b1r) ----
        {
            float hacc[4][4];
            {
                const float bj0 = b1r[cb], bj1 = b1r[cb + 1], bj2 = b1r[cb + 2], bj3 = b1r[cb + 3];
                #pragma unroll
                for (int i = 0; i < 4; ++i) {
                    hacc[i][0] = bj0; hacc[i][1] = bj1; hacc[i][2] = bj2; hacc[i][3] = bj3;
                }
            }
            #pragma unroll 2
            for (int k0 = 0; k0 < 32; k0 += 4) {
                const float4 x0 = *reinterpret_cast<const float4*>(&rbf_t[e4 + 0][k0]);
                const float4 x1 = *reinterpret_cast<const float4*>(&rbf_t[e4 + 1][k0]);
                const float4 x2 = *reinterpret_cast<const float4*>(&rbf_t[e4 + 2][k0]);
                const float4 x3 = *reinterpret_cast<const float4*>(&rbf_t[e4 + 3][k0]);
                float4 w4;
                w4 = *reinterpret_cast<const float4*>(&wbuf[k0 + 0][cb]);
                FMA_ROW(hacc[0], x0.x, w4) FMA_ROW(hacc[1], x1.x, w4)
                FMA_ROW(hacc[2], x2.x, w4) FMA_ROW(hacc[3], x3.x, w4)
                w4 = *reinterpret_cast<const float4*>(&wbuf[k0 + 1][cb]);
                FMA_ROW(hacc[0], x0.y, w4) FMA_ROW(hacc[1], x1.y, w4)
                FMA_ROW(hacc[2], x2.y, w4) FMA_ROW(hacc[3], x3.y, w4)
                w4 = *reinterpret_cast<const float4*>(&wbuf[k0 + 2][cb]);
                FMA_ROW(hacc[0], x0.z, w4) FMA_ROW(hacc[1], x1.z, w4)
                FMA_ROW(hacc[2], x2.z, w4) FMA_ROW(hacc[3], x3.z, w4)
                w4 = *reinterpret_cast<const float4*>(&wbuf[k0 + 3][cb]);
                FMA_ROW(hacc[0], x0.w, w4) FMA_ROW(hacc[1], x1.w, w4)
                FMA_ROW(hacc[2], x2.w, w4) FMA_ROW(hacc[3], x3.w, w4)
            }
            #pragma unroll
            for (int i = 0; i < 4; ++i) {
                float4 hv;
                hv.x = silu_f(hacc[i][0]); hv.y = silu_f(hacc[i][1]);
                hv.z = silu_f(hacc[i][2]); hv.w = silu_f(hacc[i][3]);
                *reinterpret_cast<float4*>(&h1[e4 + i][cb]) = hv;
            }
        }
        // he1 = silu(evinv @ w1e + b1e)
        for (int i = tid; i < TE * 32; i += 256) {
            const int e = i >> 5, j2 = i & 31;
            float a = b1e[j2];
            #pragma unroll
            for (int k = 0; k < 4; ++k) a += evinv_t[e][k] * w1e_s[k * 32 + j2];
            he1[e][j2] = silu_f(a);
        }
        __syncthreads();

        // ---- stage 2: fw = h1 @ w2r + he1 @ w2e + biases (registers) ----
        float acc[4][4];
        {
            const float b0 = b2r[cb] + b2e[cb];
            const float b1 = b2r[cb + 1] + b2e[cb + 1];
            const float b2 = b2r[cb + 2] + b2e[cb + 2];
            const float b3 = b2r[cb + 3] + b2e[cb + 3];
            #pragma unroll
            for (int i = 0; i < 4; ++i) {
                acc[i][0] = b0; acc[i][1] = b1; acc[i][2] = b2; acc[i][3] = b3;
            }
        }
        for (int cc = 0; cc < 4; ++cc) {
            {
                const float4* src = reinterpret_cast<const float4*>(w2r + cc * 4096);
                float4* dst = reinterpret_cast<float4*>(&wbuf[0][0]);
                #pragma unroll
                for (int i = 0; i < 4; ++i) dst[tid + 256 * i] = src[tid + 256 * i];
            }
            __syncthreads();
            const int cs = cc * 32;
            #pragma unroll 2
            for (int k0 = 0; k0 < 32; k0 += 4) {
                const float4 x0 = *reinterpret_cast<const float4*>(&h1[e4 + 0][cs + k0]);
                const float4 x1 = *reinterpret_cast<const float4*>(&h1[e4 + 1][cs + k0]);
                const float4 x2 = *reinterpret_cast<const float4*>(&h1[e4 + 2][cs + k0]);
                const float4 x3 = *reinterpret_cast<const float4*>(&h1[e4 + 3][cs + k0]);
                float4 w4;
                w4 = *reinterpret_cast<const float4*>(&wbuf[k0 + 0][cb]);
                FMA_ROW(acc[0], x0.x, w4) FMA_ROW(acc[1], x1.x, w4)
                FMA_ROW(acc[2], x2.x, w4) FMA_ROW(acc[3], x3.x, w4)
                w4 = *reinterpret_cast<const float4*>(&wbuf[k0 + 1][cb]);
                FMA_ROW(acc[0], x0.y, w4) FMA_ROW(acc[1], x1.y, w4)
                FMA_ROW(acc[2], x2.y, w4) FMA_ROW(acc[3], x3.y, w4)
                w4 = *reinterpret_cast<const float4*>(&wbuf[k0 + 2][cb]);
                FMA_ROW(acc[0], x0.z, w4) FMA_ROW(acc[1], x1.z, w4)
                FMA_ROW(acc[2], x2.z, w4) FMA_ROW(acc[3], x3.z, w4)
                w4 = *reinterpret_cast<const float4*>(&wbuf[k0 + 3][cb]);
                FMA_ROW(acc[0], x0.w, w4) FMA_ROW(acc[1], x1.w, w4)
                FMA_ROW(acc[2], x2.w, w4) FMA_ROW(acc[3], x3.w, w4)
            }
            __syncthreads();
        }
        // w2e chunk (he1 operand)
        {
            const float4* src = reinterpret_cast<const float4*>(w2e);
            float4* dst = reinterpret_cast<float4*>(&wbuf[0][0]);
            #pragma unroll
            for (int i = 0; i < 4; ++i) dst[tid + 256 * i] = src[tid + 256 * i];
        }
        __syncthreads();
        #pragma unroll 2
        for (int k0 = 0; k0 < 32; k0 += 4) {
            const float4 x0 = *reinterpret_cast<const float4*>(&he1[e4 + 0][k0]);
            const float4 x1 = *reinterpret_cast<const float4*>(&he1[e4 + 1][k0]);
            const float4 x2 = *reinterpret_cast<const float4*>(&he1[e4 + 2][k0]);
            const float4 x3 = *reinterpret_cast<const float4*>(&he1[e4 + 3][k0]);
            float4 w4;
            w4 = *reinterpret_cast<const float4*>(&wbuf[k0 + 0][cb]);
            FMA_ROW(acc[0], x0.x, w4) FMA_ROW(acc[1], x1.x, w4)
            FMA_ROW(acc[2], x2.x, w4) FMA_ROW(acc[3], x3.x, w4)
            w4 = *reinterpret_cast<const float4*>(&wbuf[k0 + 1][cb]);
            FMA_ROW(acc[0], x0.y, w4) FMA_ROW(acc[1], x1.y, w4)
            FMA_ROW(acc[2], x2.y, w4) FMA_ROW(acc[3], x3.y, w4)
            w4 = *reinterpret_cast<const float4*>(&wbuf[k0 + 2][cb]);
            FMA_ROW(acc[0], x0.z, w4) FMA_ROW(acc[1], x1.z, w4)
            FMA_ROW(acc[2], x2.z, w4) FMA_ROW(acc[3], x3.z, w4)
            w4 = *reinterpret_cast<const float4*>(&wbuf[k0 + 3][cb]);
            FMA_ROW(acc[0], x0.w, w4) FMA_ROW(acc[1], x1.w, w4)
            FMA_ROW(acc[2], x2.w, w4) FMA_ROW(acc[3], x3.w, w4)
        }
        __syncthreads();

        // ---- attention alphas ----
        if (p == 0) {
            #pragma unroll
            for (int i = 0; i < 4; ++i) {
                const int e = e4 + i;
                const int s = sidx[e], r = ridx[e];
                const float4 q4 = *reinterpret_cast<const float4*>(q_inv + r * 128 + cb);
                const float4 k4 = *reinterpret_cast<const float4*>(k_inv + s * 128 + cb);
                float part = q4.x * k4.x * acc[i][0] + q4.y * k4.y * acc[i][1]
                           + q4.z * k4.z * acc[i][2] + q4.w * k4.w * acc[i][3];
                part += __shfl_xor(part, 1);
                part += __shfl_xor(part, 2);
                if ((cg & 3) == 0)
                    alpha_s[e][cg >> 2] = part * 0.25f * cut[e];   // /sqrt(16)*cutoff
            }
        } else {
            #pragma unroll
            for (int i = 0; i < 4; ++i) {
                const int e = e4 + i;
                const int s = sidx[e], r = ridx[e];
                const float4 q4 = *reinterpret_cast<const float4*>(q_ev + r * 128 + cb);
                const float4 k4 = *reinterpret_cast<const float4*>(k_ev + s * 128 + cb);
                float part = q4.x * k4.x * acc[i][0] + q4.y * k4.y * acc[i][1]
                           + q4.z * k4.z * acc[i][2] + q4.w * k4.w * acc[i][3];
                part += __shfl_xor(part, 1);
                part += __shfl_xor(part, 2);
                part += __shfl_xor(part, 4);
                if ((cg & 7) == 0)
                    alpha_s[e][8 + (cg >> 3)] = part * 0.17677669529663687f * cut[e];
            }
        }
        __syncthreads();
    }

    // coalesced write of per-edge alpha records (64B each)
    for (int i = tid; i < TE * 16; i += 256) {
        const int j = i & 15;
        alpha_g[e0 * 16 + i] = (j < 12) ? alpha_s[i >> 4][j] : 0.f;
    }
}

// ---------------------------------------------------------------------------
// Kernel 3: per-node gather (CSR) + final 132x132 MLP, fused
// ---------------------------------------------------------------------------
__global__ __launch_bounds__(128) void node_update(
    const float* __restrict__ inv, const float* __restrict__ ev,
    const float* __restrict__ v_inv, const float* __restrict__ sh,
    const float* __restrict__ alpha_g,
    const int* __restrict__ cnt, const int* __restrict__ off,
    const int* __restrict__ s_eid, const int* __restrict__ s_sid,
    const float* __restrict__ int_w, const float* __restrict__ int_b,
    float* __restrict__ out0, float* __restrict__ out1)
{
    const int n = blockIdx.x;
    const int t = threadIdx.x;
    const int d = cnt[n];
    const int o = off[n];

    float acc_inv = 0.f;
    float acc_ev = 0.f;
    const int hsel = t >> 4;
    const int esel = (t < 16) ? (8 + degmap(t)) : 0;

    for (int i = 0; i < d; ++i) {
        const int p = o + i;
        const int eid = s_eid[p];
        const int sid = s_sid[p];
        const float al = alpha_g[eid * 16 + hsel];
        acc_inv += al * v_inv[sid * 128 + t];
        if (t < 16) {
            const float ae = alpha_g[eid * 16 + esel];
            acc_ev += ae * sh[eid * 16 + t];
        }
    }

    __shared__ float xin[132];
    __shared__ float ev1s[16];
    __shared__ float tcol[4];

    const float iv = inv[n * 128 + t] + acc_inv;
    xin[t] = iv;
    if (t < 16) ev1s[t] = ev[n * 16 + t] + acc_ev;
    __syncthreads();
    if (t < 4) {
        const int st = (t == 0) ? 0 : (t == 1) ? 1 : (t == 2) ? 4 : 9;
        const int en = (t == 0) ? 1 : (t == 1) ? 4 : (t == 2) ? 9 : 16;
        float a = 0.f;
        for (int j = st; j < en; ++j) a += ev1s[j] * ev1s[j];
        xin[128 + t] = a;
    }
    __syncthreads();

    float acc = int_b[t];
    for (int k = 0; k < 132; ++k) acc += xin[k] * int_w[k * 132 + t];
    out0[n * 128 + t] = iv + acc;

    if (t < 4) {
        float a2 = int_b[128 + t];
        for (int k = 0; k < 132; ++k) a2 += xin[k] * int_w[k * 132 + 128 + t];
        tcol[t] = a2;
    }
    __syncthreads();
    if (t < 16) out1[n * 16 + t] = ev1s[t] * (1.0f + tcol[degmap(t)]);
}

// ---------------------------------------------------------------------------
extern "C" void kernel_launch(void* const* d_in, const int* in_sizes, int n_in,
                              void* d_out, int out_size, void* d_ws, size_t ws_size,
                              hipStream_t stream) {
    const float* inv_features = (const float*)d_in[0];
    const float* ev_features  = (const float*)d_in[1];
    const float* rbf          = (const float*)d_in[2];
    const float* sh_vectors   = (const float*)d_in[3];
    const float* cutoffs      = (const float*)d_in[4];
    const int*   senders      = (const int*)d_in[5];
    const int*   receivers    = (const int*)d_in[6];
    const float* fi_rbf_w1 = (const float*)d_in[7];
    const float* fi_rbf_b1 = (const float*)d_in[8];
    const float* fi_rbf_w2 = (const float*)d_in[9];
    const float* fi_rbf_b2 = (const float*)d_in[10];
    const float* fi_ev_w1  = (const float*)d_in[11];
    const float* fi_ev_b1  = (const float*)d_in[12];
    const float* fi_ev_w2  = (const float*)d_in[13];
    const float* fi_ev_b2  = (const float*)d_in[14];
    const float* fe_rbf_w1 = (const float*)d_in[15];
    const float* fe_rbf_b1 = (const float*)d_in[16];
    const float* fe_rbf_w2 = (const float*)d_in[17];
    const float* fe_rbf_b2 = (const float*)d_in[18];
    const float* fe_ev_w1  = (const float*)d_in[19];
    const float* fe_ev_b1  = (const float*)d_in[20];
    const float* fe_ev_w2  = (const float*)d_in[21];
    const float* fe_ev_b2  = (const float*)d_in[22];
    const float* Wq_inv = (const float*)d_in[23];
    const float* Wk_inv = (const float*)d_in[24];
    const float* Wv_inv = (const float*)d_in[25];
    const float* Wq_ev  = (const float*)d_in[26];
    const float* Wk_ev  = (const float*)d_in[27];
    const float* int_w  = (const float*)d_in[28];
    const float* int_b  = (const float*)d_in[29];

    float* ws = (float*)d_ws;
    float* q_inv   = ws;
    float* k_inv   = ws + (size_t)NN * 128;
    float* v_inv   = ws + (size_t)NN * 256;
    float* q_ev    = ws + (size_t)NN * 384;
    float* k_ev    = ws + (size_t)NN * 512;
    float* alpha_g = ws + (size_t)NN * 640;              // E*16 = NN*256 floats
    int*   cnt     = (int*)(ws + (size_t)NN * 896);      // NN
    int*   off     = cnt + NN;                            // NN
    int*   cursor  = cnt + 2 * NN;                        // NN
    int*   s_eid   = cnt + 3 * NN;                        // EE
    int*   s_sid   = s_eid + EE;                          // EE

    hipMemsetAsync(cnt, 0, (size_t)3 * NN * sizeof(int), stream);

    node_proj<<<NN, 128, 0, stream>>>(inv_features, Wq_inv, Wk_inv, Wv_inv,
                                      Wq_ev, Wk_ev, q_inv, k_inv, v_inv, q_ev, k_ev);

    csr_count<<<EE / 256, 256, 0, stream>>>(receivers, cnt);
    csr_scan<<<1, 256, 0, stream>>>(cnt, off);
    csr_fill<<<EE / 256, 256, 0, stream>>>(receivers, senders, off, cursor, s_eid, s_sid);

    edge_kernel<<<EE / TE, 256, 0, stream>>>(
        ev_features, rbf, cutoffs, senders, receivers,
        fi_rbf_w1, fi_rbf_b1, fi_rbf_w2, fi_rbf_b2,
        fi_ev_w1, fi_ev_b1, fi_ev_w2, fi_ev_b2,
        fe_rbf_w1, fe_rbf_b1, fe_rbf_w2, fe_rbf_b2,
        fe_ev_w1, fe_ev_b1, fe_ev_w2, fe_ev_b2,
        q_inv, k_inv, q_ev, k_ev, alpha_g);

    node_update<<<NN, 128, 0, stream>>>(inv_features, ev_features, v_inv, sh_vectors,
                                        alpha_g, cnt, off, s_eid, s_sid,
                                        int_w, int_b,
                                        (float*)d_out, (float*)d_out + (size_t)NN * 128);
}

// Round 4
// 440.152 us; speedup vs baseline: 10.2893x; 1.6138x over previous
//
#include <hip/hip_runtime.h>
#include <math.h>

#define NN 16384
#define FF 128
#define NRB 32
#define EE 262144
#define TE 32

typedef __attribute__((ext_vector_type(8))) short short8v;   // 8 bf16 = 4 VGPRs
typedef __attribute__((ext_vector_type(4))) float f32x4;

__device__ __forceinline__ float silu_f(float x) { return x / (1.0f + expf(-x)); }
__device__ __forceinline__ int degmap(int j) { return (j == 0) ? 0 : (j < 4) ? 1 : (j < 9) ? 2 : 3; }
__device__ __forceinline__ unsigned short f2b(float f) {
    unsigned int u = __float_as_uint(f);
    unsigned int r = (u + 0x7FFFu + ((u >> 16) & 1u)) >> 16;
    return (unsigned short)r;
}

// ---------------------------------------------------------------------------
// Weight prep: transpose + convert filter weights to bf16.
// Layout per filter p: w1rT[128][32] | w2rT[128][128] | w2eT[128][32]
//   (row = output col c, inner = k, so B-fragments are 16B-contiguous)
// ---------------------------------------------------------------------------
__global__ __launch_bounds__(256) void prep_weights(
    const float* __restrict__ fi_w1r, const float* __restrict__ fi_w2r,
    const float* __restrict__ fi_w2e,
    const float* __restrict__ fe_w1r, const float* __restrict__ fe_w2r,
    const float* __restrict__ fe_w2e,
    unsigned short* __restrict__ wbf)
{
    const int id = blockIdx.x * 256 + threadIdx.x;   // 49152 total
    if (id >= 2 * 24576) return;
    const int p = id / 24576;
    const int r = id % 24576;
    const float* w1r = p ? fe_w1r : fi_w1r;
    const float* w2r = p ? fe_w2r : fi_w2r;
    const float* w2e = p ? fe_w2e : fi_w2e;
    float v;
    if (r < 4096) {               // w1rT: c = r>>5, k = r&31
        v = w1r[(r & 31) * 128 + (r >> 5)];
    } else if (r < 20480) {       // w2rT: c = rr>>7, k = rr&127
        const int rr = r - 4096;
        v = w2r[(rr & 127) * 128 + (rr >> 7)];
    } else {                      // w2eT: c = rr>>5, k = rr&31
        const int rr = r - 20480;
        v = w2e[(rr & 31) * 128 + (rr >> 5)];
    }
    wbf[p * 24576 + r] = f2b(v);
}

// ---------------------------------------------------------------------------
// Kernel 1: per-node projections q/k/v_inv (8 heads of 16x16), q/k_ev (4 of 32x32)
// ---------------------------------------------------------------------------
__global__ __launch_bounds__(128) void node_proj(
    const float* __restrict__ inv,
    const float* __restrict__ Wq_inv, const float* __restrict__ Wk_inv,
    const float* __restrict__ Wv_inv,
    const float* __restrict__ Wq_ev, const float* __restrict__ Wk_ev,
    float* __restrict__ q_inv, float* __restrict__ k_inv, float* __restrict__ v_inv,
    float* __restrict__ q_ev, float* __restrict__ k_ev)
{
    const int n = blockIdx.x;
    const int t = threadIdx.x;
    __shared__ float x[128];
    x[t] = inv[n * 128 + t];
    __syncthreads();

    {
        const int h = t >> 4, e = t & 15;
        const float* wq = Wq_inv + h * 256;
        const float* wk = Wk_inv + h * 256;
        const float* wv = Wv_inv + h * 256;
        float aq = 0.f, ak = 0.f, av = 0.f;
        #pragma unroll
        for (int d = 0; d < 16; ++d) {
            const float xv = x[h * 16 + d];
            aq += xv * wq[d * 16 + e];
            ak += xv * wk[d * 16 + e];
            av += xv * wv[d * 16 + e];
        }
        q_inv[n * 128 + t] = aq;
        k_inv[n * 128 + t] = ak;
        v_inv[n * 128 + t] = av;
    }
    {
        const int l = t >> 5, e = t & 31;
        const float* wq = Wq_ev + l * 1024;
        const float* wk = Wk_ev + l * 1024;
        float aq = 0.f, ak = 0.f;
        #pragma unroll
        for (int d = 0; d < 32; ++d) {
            const float xv = x[l * 32 + d];
            aq += xv * wq[d * 32 + e];
            ak += xv * wk[d * 32 + e];
        }
        q_ev[n * 128 + t] = aq;
        k_ev[n * 128 + t] = ak;
    }
}

// ---------------------------------------------------------------------------
// CSR build kernels
// ---------------------------------------------------------------------------
__global__ __launch_bounds__(256) void csr_count(const int* __restrict__ recv,
                                                 int* __restrict__ cnt) {
    const int e = blockIdx.x * 256 + threadIdx.x;
    if (e < EE) atomicAdd(&cnt[recv[e]], 1);
}

__global__ __launch_bounds__(256) void csr_scan(const int* __restrict__ cnt,
                                                int* __restrict__ off) {
    __shared__ int ps[256];
    const int t = threadIdx.x;
    const int base = t * 64;
    int s = 0;
    for (int i = 0; i < 64; ++i) s += cnt[base + i];
    ps[t] = s;
    __syncthreads();
    for (int dd = 1; dd < 256; dd <<= 1) {
        int v = 0;
        if (t >= dd) v = ps[t - dd];
        __syncthreads();
        ps[t] += v;
        __syncthreads();
    }
    int run = ps[t] - s;  // exclusive prefix
    for (int i = 0; i < 64; ++i) {
        off[base + i] = run;
        run += cnt[base + i];
    }
}

__global__ __launch_bounds__(256) void csr_fill(const int* __restrict__ recv,
                                                const int* __restrict__ send,
                                                const int* __restrict__ off,
                                                int* __restrict__ cursor,
                                                int* __restrict__ s_eid,
                                                int* __restrict__ s_sid) {
    const int e = blockIdx.x * 256 + threadIdx.x;
    if (e < EE) {
        const int r = recv[e];
        const int p = off[r] + atomicAdd(&cursor[r], 1);
        s_eid[p] = e;
        s_sid[p] = send[e];
    }
}

// ---------------------------------------------------------------------------
// Kernel 2: MFMA edge kernel. 32 edges/block, 256 thr = 4 waves.
//   Wave w: M-tile mt=w&1 (16 edges), N-tiles tg*4..tg*4+3 (tg=w>>1).
//   mfma_f32_16x16x32_bf16; A from LDS (bf16, padded rows), B from global
//   (pre-transposed bf16 weights). alpha records: 12 floats/edge.
// ---------------------------------------------------------------------------
__global__ __launch_bounds__(256) void edge_kernel(
    const float* __restrict__ ev_feat,
    const float* __restrict__ rbf,
    const float* __restrict__ cutoffs,
    const int* __restrict__ senders,
    const int* __restrict__ receivers,
    const unsigned short* __restrict__ wbf,
    const float* __restrict__ fi_b1r, const float* __restrict__ fi_b2r,
    const float* __restrict__ fi_w1e, const float* __restrict__ fi_b1e,
    const float* __restrict__ fi_b2e,
    const float* __restrict__ fe_b1r, const float* __restrict__ fe_b2r,
    const float* __restrict__ fe_w1e, const float* __restrict__ fe_b1e,
    const float* __restrict__ fe_b2e,
    const float* __restrict__ q_inv, const float* __restrict__ k_inv,
    const float* __restrict__ q_ev, const float* __restrict__ k_ev,
    float* __restrict__ alpha_g)
{
    __shared__ unsigned short rbuf[32][40];    // rbf bf16, padded (80B rows)
    __shared__ unsigned short h1buf[32][136];  // h1 bf16, padded (272B rows)
    __shared__ unsigned short hebuf[32][40];   // he1 bf16
    __shared__ float evinv_t[32][4];
    __shared__ float alpha_s[32][12];
    __shared__ int sidx[32];
    __shared__ int ridx[32];
    __shared__ float cut[32];

    const int tid = threadIdx.x;
    const int e0 = blockIdx.x * TE;
    const int lane = tid & 63;
    const int w = tid >> 6;
    const int mt = w & 1;
    const int tg = w >> 1;
    const int lrow = lane & 15;
    const int lk = lane >> 4;

    if (tid < 32) {
        sidx[tid] = senders[e0 + tid];
        ridx[tid] = receivers[e0 + tid];
        cut[tid] = cutoffs[e0 + tid];
        // evinv (same thread wrote sidx/ridx -> no barrier needed)
        const float* es = ev_feat + (size_t)sidx[tid] * 16;
        const float* er = ev_feat + (size_t)ridx[tid] * 16;
        float d = es[0] - er[0];
        evinv_t[tid][0] = d * d;
        float a = 0.f;
        for (int j = 1; j < 4; ++j) { d = es[j] - er[j]; a += d * d; }
        evinv_t[tid][1] = a;
        a = 0.f;
        for (int j = 4; j < 9; ++j) { d = es[j] - er[j]; a += d * d; }
        evinv_t[tid][2] = a;
        a = 0.f;
        for (int j = 9; j < 16; ++j) { d = es[j] - er[j]; a += d * d; }
        evinv_t[tid][3] = a;
    }
    // rbf -> bf16 LDS: thread handles 4 consecutive elements
    {
        const float4 rv = *reinterpret_cast<const float4*>(rbf + (size_t)e0 * 32 + tid * 4);
        unsigned short* dst = &rbuf[tid >> 3][(tid & 7) * 4];
        dst[0] = f2b(rv.x); dst[1] = f2b(rv.y); dst[2] = f2b(rv.z); dst[3] = f2b(rv.w);
    }
    __syncthreads();

    for (int p = 0; p < 2; ++p) {
        const unsigned short* w1rT = wbf + p * 24576;
        const unsigned short* w2rT = w1rT + 4096;
        const unsigned short* w2eT = w1rT + 20480;
        const float* b1r = p ? fe_b1r : fi_b1r;
        const float* b2r = p ? fe_b2r : fi_b2r;
        const float* w1e = p ? fe_w1e : fi_w1e;
        const float* b1e = p ? fe_b1e : fi_b1e;
        const float* b2e = p ? fe_b2e : fi_b2e;

        // ---- stage 1: h1 = silu(rbf @ w1r + b1r), via MFMA ----
        {
            const short8v a1 = *reinterpret_cast<const short8v*>(&rbuf[mt * 16 + lrow][lk * 8]);
            f32x4 acc1[4];
            #pragma unroll
            for (int t = 0; t < 4; ++t) {
                const int col = (tg * 4 + t) * 16 + lrow;
                const float b = b1r[col];
                acc1[t][0] = b; acc1[t][1] = b; acc1[t][2] = b; acc1[t][3] = b;
                const short8v bf = *reinterpret_cast<const short8v*>(
                    w1rT + (size_t)col * 32 + lk * 8);
                acc1[t] = __builtin_amdgcn_mfma_f32_16x16x32_bf16(a1, bf, acc1[t], 0, 0, 0);
            }
            #pragma unroll
            for (int t = 0; t < 4; ++t) {
                const int col = (tg * 4 + t) * 16 + lrow;
                #pragma unroll
                for (int rg = 0; rg < 4; ++rg) {
                    const int row = mt * 16 + lk * 4 + rg;
                    h1buf[row][col] = f2b(silu_f(acc1[t][rg]));
                }
            }
        }
        // ---- he1 = silu(evinv @ w1e + b1e): thread -> 4 consecutive j ----
        {
            const int e = tid >> 3;
            const int j4 = (tid & 7) * 4;
            const float ev0 = evinv_t[e][0], ev1 = evinv_t[e][1];
            const float ev2 = evinv_t[e][2], ev3 = evinv_t[e][3];
            #pragma unroll
            for (int jj = 0; jj < 4; ++jj) {
                const int j = j4 + jj;
                float a = b1e[j] + ev0 * w1e[j] + ev1 * w1e[32 + j]
                        + ev2 * w1e[64 + j] + ev3 * w1e[96 + j];
                hebuf[e][j] = f2b(silu_f(a));
            }
        }
        __syncthreads();

        // ---- stage 2: fw = h1 @ w2r + he1 @ w2e + b2r + b2e ----
        f32x4 acc[4];
        #pragma unroll
        for (int t = 0; t < 4; ++t) {
            const int col = (tg * 4 + t) * 16 + lrow;
            const float b = b2r[col] + b2e[col];
            acc[t][0] = b; acc[t][1] = b; acc[t][2] = b; acc[t][3] = b;
        }
        #pragma unroll
        for (int ks = 0; ks < 4; ++ks) {
            const short8v a = *reinterpret_cast<const short8v*>(
                &h1buf[mt * 16 + lrow][ks * 32 + lk * 8]);
            #pragma unroll
            for (int t = 0; t < 4; ++t) {
                const int col = (tg * 4 + t) * 16 + lrow;
                const short8v bf = *reinterpret_cast<const short8v*>(
                    w2rT + (size_t)col * 128 + ks * 32 + lk * 8);
                acc[t] = __builtin_amdgcn_mfma_f32_16x16x32_bf16(a, bf, acc[t], 0, 0, 0);
            }
        }
        {
            const short8v ae = *reinterpret_cast<const short8v*>(&hebuf[mt * 16 + lrow][lk * 8]);
            #pragma unroll
            for (int t = 0; t < 4; ++t) {
                const int col = (tg * 4 + t) * 16 + lrow;
                const short8v bf = *reinterpret_cast<const short8v*>(
                    w2eT + (size_t)col * 32 + lk * 8);
                acc[t] = __builtin_amdgcn_mfma_f32_16x16x32_bf16(ae, bf, acc[t], 0, 0, 0);
            }
        }

        // ---- attention alphas from C fragments ----
        if (p == 0) {
            #pragma unroll
            for (int t = 0; t < 4; ++t) {
                const int head = tg * 4 + t;
                const int col = head * 16 + lrow;
                #pragma unroll
                for (int rg = 0; rg < 4; ++rg) {
                    const int e = mt * 16 + lk * 4 + rg;
                    const int r = ridx[e], s = sidx[e];
                    float part = q_inv[(size_t)r * 128 + col]
                               * k_inv[(size_t)s * 128 + col] * acc[t][rg];
                    part += __shfl_xor(part, 1);
                    part += __shfl_xor(part, 2);
                    part += __shfl_xor(part, 4);
                    part += __shfl_xor(part, 8);
                    if (lrow == 0) alpha_s[e][head] = part * 0.25f * cut[e];
                }
            }
        } else {
            float pt[4][4];
            #pragma unroll
            for (int t = 0; t < 4; ++t) {
                const int col = (tg * 4 + t) * 16 + lrow;
                #pragma unroll
                for (int rg = 0; rg < 4; ++rg) {
                    const int e = mt * 16 + lk * 4 + rg;
                    const int r = ridx[e], s = sidx[e];
                    float part = q_ev[(size_t)r * 128 + col]
                               * k_ev[(size_t)s * 128 + col] * acc[t][rg];
                    part += __shfl_xor(part, 1);
                    part += __shfl_xor(part, 2);
                    part += __shfl_xor(part, 4);
                    part += __shfl_xor(part, 8);
                    pt[t][rg] = part;
                }
            }
            #pragma unroll
            for (int d2 = 0; d2 < 2; ++d2) {
                const int deg = tg * 2 + d2;
                #pragma unroll
                for (int rg = 0; rg < 4; ++rg) {
                    const int e = mt * 16 + lk * 4 + rg;
                    const float v = pt[2 * d2][rg] + pt[2 * d2 + 1][rg];
                    if (lrow == 0)
                        alpha_s[e][8 + deg] = v * 0.17677669529663687f * cut[e];
                }
            }
        }
        __syncthreads();
    }

    // coalesced write of per-edge alpha records (48B each)
    const float* aflat = &alpha_s[0][0];
    for (int i = tid; i < TE * 12; i += 256)
        alpha_g[(size_t)e0 * 12 + i] = aflat[i];
}

// ---------------------------------------------------------------------------
// Kernel 3: per-node gather (CSR) + final 132x132 MLP, fused
// ---------------------------------------------------------------------------
__global__ __launch_bounds__(128) void node_update(
    const float* __restrict__ inv, const float* __restrict__ ev,
    const float* __restrict__ v_inv, const float* __restrict__ sh,
    const float* __restrict__ alpha_g,
    const int* __restrict__ cnt, const int* __restrict__ off,
    const int* __restrict__ s_eid, const int* __restrict__ s_sid,
    const float* __restrict__ int_w, const float* __restrict__ int_b,
    float* __restrict__ out0, float* __restrict__ out1)
{
    const int n = blockIdx.x;
    const int t = threadIdx.x;
    const int d = cnt[n];
    const int o = off[n];

    float acc_inv = 0.f;
    float acc_ev = 0.f;
    const int hsel = t >> 4;
    const int esel = (t < 16) ? (8 + degmap(t)) : 0;

    for (int i = 0; i < d; ++i) {
        const int p = o + i;
        const int eid = s_eid[p];
        const int sid = s_sid[p];
        const float al = alpha_g[(size_t)eid * 12 + hsel];
        acc_inv += al * v_inv[(size_t)sid * 128 + t];
        if (t < 16) {
            const float ae = alpha_g[(size_t)eid * 12 + esel];
            acc_ev += ae * sh[(size_t)eid * 16 + t];
        }
    }

    __shared__ float xin[132];
    __shared__ float ev1s[16];
    __shared__ float tcol[4];

    const float iv = inv[n * 128 + t] + acc_inv;
    xin[t] = iv;
    if (t < 16) ev1s[t] = ev[n * 16 + t] + acc_ev;
    __syncthreads();
    if (t < 4) {
        const int st = (t == 0) ? 0 : (t == 1) ? 1 : (t == 2) ? 4 : 9;
        const int en = (t == 0) ? 1 : (t == 1) ? 4 : (t == 2) ? 9 : 16;
        float a = 0.f;
        for (int j = st; j < en; ++j) a += ev1s[j] * ev1s[j];
        xin[128 + t] = a;
    }
    __syncthreads();

    float acc = int_b[t];
    for (int k = 0; k < 132; ++k) acc += xin[k] * int_w[k * 132 + t];
    out0[n * 128 + t] = iv + acc;

    if (t < 4) {
        float a2 = int_b[128 + t];
        for (int k = 0; k < 132; ++k) a2 += xin[k] * int_w[k * 132 + 128 + t];
        tcol[t] = a2;
    }
    __syncthreads();
    if (t < 16) out1[n * 16 + t] = ev1s[t] * (1.0f + tcol[degmap(t)]);
}

// ---------------------------------------------------------------------------
extern "C" void kernel_launch(void* const* d_in, const int* in_sizes, int n_in,
                              void* d_out, int out_size, void* d_ws, size_t ws_size,
                              hipStream_t stream) {
    const float* inv_features = (const float*)d_in[0];
    const float* ev_features  = (const float*)d_in[1];
    const float* rbf          = (const float*)d_in[2];
    const float* sh_vectors   = (const float*)d_in[3];
    const float* cutoffs      = (const float*)d_in[4];
    const int*   senders      = (const int*)d_in[5];
    const int*   receivers    = (const int*)d_in[6];
    const float* fi_rbf_w1 = (const float*)d_in[7];
    const float* fi_rbf_b1 = (const float*)d_in[8];
    const float* fi_rbf_w2 = (const float*)d_in[9];
    const float* fi_rbf_b2 = (const float*)d_in[10];
    const float* fi_ev_w1  = (const float*)d_in[11];
    const float* fi_ev_b1  = (const float*)d_in[12];
    const float* fi_ev_w2  = (const float*)d_in[13];
    const float* fi_ev_b2  = (const float*)d_in[14];
    const float* fe_rbf_w1 = (const float*)d_in[15];
    const float* fe_rbf_b1 = (const float*)d_in[16];
    const float* fe_rbf_w2 = (const float*)d_in[17];
    const float* fe_rbf_b2 = (const float*)d_in[18];
    const float* fe_ev_w1  = (const float*)d_in[19];
    const float* fe_ev_b1  = (const float*)d_in[20];
    const float* fe_ev_w2  = (const float*)d_in[21];
    const float* fe_ev_b2  = (const float*)d_in[22];
    const float* Wq_inv = (const float*)d_in[23];
    const float* Wk_inv = (const float*)d_in[24];
    const float* Wv_inv = (const float*)d_in[25];
    const float* Wq_ev  = (const float*)d_in[26];
    const float* Wk_ev  = (const float*)d_in[27];
    const float* int_w  = (const float*)d_in[28];
    const float* int_b  = (const float*)d_in[29];

    float* ws = (float*)d_ws;
    float* q_inv   = ws;
    float* k_inv   = ws + (size_t)NN * 128;
    float* v_inv   = ws + (size_t)NN * 256;
    float* q_ev    = ws + (size_t)NN * 384;
    float* k_ev    = ws + (size_t)NN * 512;
    float* alpha_g = ws + (size_t)NN * 640;              // E*12 = NN*192 floats
    int*   cnt     = (int*)(ws + (size_t)NN * 832);      // NN
    int*   off     = cnt + NN;                            // NN
    int*   cursor  = cnt + 2 * NN;                        // NN
    int*   s_eid   = cnt + 3 * NN;                        // EE
    int*   s_sid   = s_eid + EE;                          // EE
    unsigned short* wbf = (unsigned short*)(s_sid + EE);  // 49152 bf16 (16B-aligned)

    hipMemsetAsync(cnt, 0, (size_t)3 * NN * sizeof(int), stream);

    prep_weights<<<192, 256, 0, stream>>>(fi_rbf_w1, fi_rbf_w2, fi_ev_w2,
                                          fe_rbf_w1, fe_rbf_w2, fe_ev_w2, wbf);

    node_proj<<<NN, 128, 0, stream>>>(inv_features, Wq_inv, Wk_inv, Wv_inv,
                                      Wq_ev, Wk_ev, q_inv, k_inv, v_inv, q_ev, k_ev);

    csr_count<<<EE / 256, 256, 0, stream>>>(receivers, cnt);
    csr_scan<<<1, 256, 0, stream>>>(cnt, off);
    csr_fill<<<EE / 256, 256, 0, stream>>>(receivers, senders, off, cursor, s_eid, s_sid);

    edge_kernel<<<EE / TE, 256, 0, stream>>>(
        ev_features, rbf, cutoffs, senders, receivers, wbf,
        fi_rbf_b1, fi_rbf_b2, fi_ev_w1, fi_ev_b1, fi_ev_b2,
        fe_rbf_b1, fe_rbf_b2, fe_ev_w1, fe_ev_b1, fe_ev_b2,
        q_inv, k_inv, q_ev, k_ev, alpha_g);

    node_update<<<NN, 128, 0, stream>>>(inv_features, ev_features, v_inv, sh_vectors,
                                        alpha_g, cnt, off, s_eid, s_sid,
                                        int_w, int_b,
                                        (float*)d_out, (float*)d_out + (size_t)NN * 128);
}